// Round 15
// baseline (82.404 us; speedup 1.0000x reference)
//
#include <hip/hip_runtime.h>
#include <math.h>

// Problem constants (B=8, N=2048, F=64, O=64), f32 in/out.
#define BB 8
#define NN 2048
#define FF 64
#define OO 64
#define KC 128                 // K-chunk per k_main phase
#define NITER (NN / KC)        // 16 (8 double-phases)
constexpr float ALPHA = 0.2f;

typedef float  f32x4  __attribute__((ext_vector_type(4)));
typedef short  s16x8  __attribute__((ext_vector_type(8)));

// round-to-nearest-even f32 -> bf16, two packed into a u32
static __device__ __forceinline__ unsigned int packbf2(float a, float b) {
    unsigned int ua = __builtin_bit_cast(unsigned int, a);
    unsigned int ub = __builtin_bit_cast(unsigned int, b);
    ua = (ua + 0x7FFFu + ((ua >> 16) & 1u)) >> 16;
    ub = (ub + 0x7FFFu + ((ub >> 16) & 1u)) & 0xFFFF0000u;
    return ua | ub;
}

// ---------------------------------------------------------------------------
// k_copy4: 4096 blocks x 256 threads, 4 rows/block, barrier-free.
// NT LOADS of A (don't allocate in L2/L3) + PLAIN stores of Ac (allocate).
// Steady-state L3 then holds Ac only (134 MB, fits): Ac stores hit their own
// dirty lines (no HBM writeback during timing), A streams read-only from HBM
// -> per-replay HBM traffic ~halves vs the plain-load thrash regime.
// ---------------------------------------------------------------------------
__global__ __launch_bounds__(256) void k_copy4(const float* __restrict__ A,
                                               float* __restrict__ Ac,
                                               float* __restrict__ dsum4) {
    const size_t base = (size_t)blockIdx.x * 8192;   // 4 rows of 2048 f32
    const int t = threadIdx.x;
    const float* a = A  + base;
    float*       c = Ac + base;

    f32x4 v0 = __builtin_nontemporal_load((const f32x4*)(a + 0 * 1024 + t * 4));
    f32x4 v1 = __builtin_nontemporal_load((const f32x4*)(a + 1 * 1024 + t * 4));
    f32x4 v2 = __builtin_nontemporal_load((const f32x4*)(a + 2 * 1024 + t * 4));
    f32x4 v3 = __builtin_nontemporal_load((const f32x4*)(a + 3 * 1024 + t * 4));
    f32x4 v4 = __builtin_nontemporal_load((const f32x4*)(a + 4 * 1024 + t * 4));
    f32x4 v5 = __builtin_nontemporal_load((const f32x4*)(a + 5 * 1024 + t * 4));
    f32x4 v6 = __builtin_nontemporal_load((const f32x4*)(a + 6 * 1024 + t * 4));
    f32x4 v7 = __builtin_nontemporal_load((const f32x4*)(a + 7 * 1024 + t * 4));

    *(f32x4*)(c + 0 * 1024 + t * 4) = v0;
    *(f32x4*)(c + 1 * 1024 + t * 4) = v1;
    *(f32x4*)(c + 2 * 1024 + t * 4) = v2;
    *(f32x4*)(c + 3 * 1024 + t * 4) = v3;
    *(f32x4*)(c + 4 * 1024 + t * 4) = v4;
    *(f32x4*)(c + 5 * 1024 + t * 4) = v5;
    *(f32x4*)(c + 6 * 1024 + t * 4) = v6;
    *(f32x4*)(c + 7 * 1024 + t * 4) = v7;

    const int lane = t & 63, w = t >> 6;
    #pragma unroll
    for (int r = 0; r < 4; ++r) {
        f32x4 p0 = (r == 0) ? v0 : (r == 1) ? v2 : (r == 2) ? v4 : v6;
        f32x4 p1 = (r == 0) ? v1 : (r == 1) ? v3 : (r == 2) ? v5 : v7;
        float s = ((p0.x + p0.y) + (p0.z + p0.w)) + ((p1.x + p1.y) + (p1.z + p1.w));
        #pragma unroll
        for (int off = 32; off > 0; off >>= 1) s += __shfl_down(s, off, 64);
        if (lane == 0) dsum4[((size_t)blockIdx.x * 4 + r) * 4 + w] = s;
    }
}

// ---------------------------------------------------------------------------
// k_xw: finishes the rowsum (dInv = rsqrt(1 + sum of 4 wave partials)),
// then Y[row,o] = dInv[row] * sum_f X[row,f] * W[f,o].
//   Yf  [b][n][o] f32   (self-term for epilogue)
//   Ytb [b][o][m] bf16  (transposed; k_main B-operand)
// ---------------------------------------------------------------------------
__global__ __launch_bounds__(256) void k_xw(const float* __restrict__ X,
                                            const float* __restrict__ W,
                                            const float* __restrict__ dsum4,
                                            float* __restrict__ dInvG,
                                            float* __restrict__ Yf,
                                            ushort* __restrict__ Ytb) {
    __shared__ float Ws[FF][OO];
    __shared__ float Xs[16][FF];
    __shared__ float dsh[16];
    const int t = threadIdx.x;
    const int r0 = blockIdx.x * 16;

    if (t < 16) {
        const float* p = dsum4 + (size_t)(r0 + t) * 4;
        float tot = p[0] + p[1] + p[2] + p[3] + 1.0f;
        float di = 1.0f / sqrtf(tot);
        dsh[t] = di;
        dInvG[r0 + t] = di;
    }
    #pragma unroll
    for (int j = 0; j < 4; ++j) {
        int f4 = t + 256 * j;
        ((float4*)Ws)[f4] = ((const float4*)W)[f4];
    }
    ((float4*)Xs)[t] = ((const float4*)(X + (size_t)r0 * FF))[t];
    __syncthreads();

    const int c = t & 63, g = t >> 6;
    float acc[4] = {0.f, 0.f, 0.f, 0.f};
    for (int f = 0; f < FF; ++f) {
        float wv = Ws[f][c];
        #pragma unroll
        for (int i = 0; i < 4; ++i) acc[i] += Xs[g * 4 + i][f] * wv;
    }
    float y[4];
    #pragma unroll
    for (int i = 0; i < 4; ++i) {
        y[i] = dsh[g * 4 + i] * acc[i];
        Yf[(size_t)(r0 + g * 4 + i) * OO + c] = y[i];
    }
    const int b = r0 >> 11;
    const int n = (r0 & (NN - 1)) + g * 4;
    *(uint2*)(Ytb + ((size_t)b * OO + c) * NN + n) =
        make_uint2(packbf2(y[0], y[1]), packbf2(y[2], y[3]));
}

// ---------------------------------------------------------------------------
// k_main (MFMA): out0[b,n,o] = leaky( dInv[n]*(sum_m Ac[n,m]*Y[m,o] + Y[n,o]) + bias[o] )
// Reads Ac = outA, just written by k_copy4 -> L3-resident (R11: ~3 us).
// No global stores in the K-loop. Depth-2 pipeline, R5-verified layout.
// ---------------------------------------------------------------------------
__global__ __launch_bounds__(256, 4) void k_main(const float* __restrict__ Ac,
                                                 const ushort* __restrict__ Ytb,
                                                 const float* __restrict__ Yf,
                                                 const float* __restrict__ dInv,
                                                 const float* __restrict__ bias,
                                                 float* __restrict__ out0) {
    __shared__ ushort As[16][136];     // 4.25 KB
    __shared__ ushort Ys[64 * 128];    // 16 KB, [o][128], XOR-swizzled

    const int bx = blockIdx.x;          // 1024
    const int b  = bx >> 7;
    const int n0 = (bx & 127) * 16;

    const float*  Ab   = Ac   + ((size_t)b * NN + n0) * NN;
    const ushort* yb   = Ytb  + (size_t)b * OO * NN;
    const float*  Yf_b = Yf   + (size_t)b * NN * OO;
    float*        O_b  = out0 + (size_t)b * NN * OO;

    const int t = threadIdx.x;
    const int lane = t & 63, w = t >> 6;
    const int fr = lane & 15, fg = lane >> 4;

    // A staging coords (2 float4/thread)
    const int ar0 = t >> 5,         ac0 = (t & 31) * 4;
    const int ar1 = (t + 256) >> 5, ac1 = (t & 31) * 4;
    const float* aSrc0 = Ab + (size_t)ar0 * NN + ac0;
    const float* aSrc1 = Ab + (size_t)ar1 * NN + ac1;

    // Y staging coords (4 uint4/thread)
    const int yrBase = w * 16 + (lane >> 4);
    const int ycu    = (lane & 15) * 8;
    const ushort* ySrc = yb + (size_t)yrBase * NN + ycu;

    // fragment read bases
    const ushort* aFragBase = &As[fr][fg * 8];
    const int yRow = w * 16 + fr;
    const int ySwz = (fr & 7) << 3;

    f32x4 acc = {0.f, 0.f, 0.f, 0.f};

    // ---- two named prefetch sets (no runtime-indexed arrays) ----
    float4 paA0, paA1, paB0, paB1;
    uint4  pyA0, pyA1, pyA2, pyA3, pyB0, pyB1, pyB2, pyB3;

    // prologue: set A <- tile 0, set B <- tile 1
    paA0 = *(const float4*)(aSrc0);
    paA1 = *(const float4*)(aSrc1);
    pyA0 = *(const uint4*)(ySrc);
    pyA1 = *(const uint4*)(ySrc + 4 * NN);
    pyA2 = *(const uint4*)(ySrc + 8 * NN);
    pyA3 = *(const uint4*)(ySrc + 12 * NN);
    paB0 = *(const float4*)(aSrc0 + KC);
    paB1 = *(const float4*)(aSrc1 + KC);
    pyB0 = *(const uint4*)(ySrc + KC);
    pyB1 = *(const uint4*)(ySrc + KC + 4 * NN);
    pyB2 = *(const uint4*)(ySrc + KC + 8 * NN);
    pyB3 = *(const uint4*)(ySrc + KC + 12 * NN);

    for (int j = 0; j < NITER / 2; ++j) {
        const int k0 = 2 * j * KC;

        // ================= phase A: consume set A (tile 2j) =================
        __builtin_amdgcn_s_barrier();
        {
            uint2 qa;
            qa.x = packbf2(paA0.x, paA0.y);
            qa.y = packbf2(paA0.z, paA0.w);
            *(uint2*)&As[ar0][ac0] = qa;
            qa.x = packbf2(paA1.x, paA1.y);
            qa.y = packbf2(paA1.z, paA1.w);
            *(uint2*)&As[ar1][ac1] = qa;
        }
        {
            const int r0w = yrBase;
            *(uint4*)&Ys[(r0w + 0) * 128 + (ycu ^ (((r0w + 0) & 7) << 3))] = pyA0;
            *(uint4*)&Ys[(r0w + 4) * 128 + (ycu ^ (((r0w + 4) & 7) << 3))] = pyA1;
            *(uint4*)&Ys[(r0w + 8) * 128 + (ycu ^ (((r0w + 8) & 7) << 3))] = pyA2;
            *(uint4*)&Ys[(r0w + 12) * 128 + (ycu ^ (((r0w + 12) & 7) << 3))] = pyA3;
        }
        asm volatile("s_waitcnt lgkmcnt(0)" ::: "memory");
        __builtin_amdgcn_sched_barrier(0);
        __builtin_amdgcn_s_barrier();

        if (j < NITER / 2 - 1) {            // refill set A <- tile 2j+2
            const int kn = k0 + 2 * KC;
            paA0 = *(const float4*)(aSrc0 + kn);
            paA1 = *(const float4*)(aSrc1 + kn);
            pyA0 = *(const uint4*)(ySrc + kn);
            pyA1 = *(const uint4*)(ySrc + kn + 4 * NN);
            pyA2 = *(const uint4*)(ySrc + kn + 8 * NN);
            pyA3 = *(const uint4*)(ySrc + kn + 12 * NN);
        }

        #pragma unroll
        for (int ks = 0; ks < 4; ++ks) {
            s16x8 af = *(const s16x8*)(aFragBase + ks * 32);
            s16x8 bf = *(const s16x8*)&Ys[yRow * 128 + ((ks * 32 + fg * 8) ^ ySwz)];
            acc = __builtin_amdgcn_mfma_f32_16x16x32_bf16(af, bf, acc, 0, 0, 0);
        }

        // ================= phase B: consume set B (tile 2j+1) ===============
        __builtin_amdgcn_s_barrier();
        {
            uint2 qa;
            qa.x = packbf2(paB0.x, paB0.y);
            qa.y = packbf2(paB0.z, paB0.w);
            *(uint2*)&As[ar0][ac0] = qa;
            qa.x = packbf2(paB1.x, paB1.y);
            qa.y = packbf2(paB1.z, paB1.w);
            *(uint2*)&As[ar1][ac1] = qa;
        }
        {
            const int r0w = yrBase;
            *(uint4*)&Ys[(r0w + 0) * 128 + (ycu ^ (((r0w + 0) & 7) << 3))] = pyB0;
            *(uint4*)&Ys[(r0w + 4) * 128 + (ycu ^ (((r0w + 4) & 7) << 3))] = pyB1;
            *(uint4*)&Ys[(r0w + 8) * 128 + (ycu ^ (((r0w + 8) & 7) << 3))] = pyB2;
            *(uint4*)&Ys[(r0w + 12) * 128 + (ycu ^ (((r0w + 12) & 7) << 3))] = pyB3;
        }
        asm volatile("s_waitcnt lgkmcnt(0)" ::: "memory");
        __builtin_amdgcn_sched_barrier(0);
        __builtin_amdgcn_s_barrier();

        if (j < NITER / 2 - 1) {            // refill set B <- tile 2j+3
            const int kn = k0 + 3 * KC;
            paB0 = *(const float4*)(aSrc0 + kn);
            paB1 = *(const float4*)(aSrc1 + kn);
            pyB0 = *(const uint4*)(ySrc + kn);
            pyB1 = *(const uint4*)(ySrc + kn + 4 * NN);
            pyB2 = *(const uint4*)(ySrc + kn + 8 * NN);
            pyB3 = *(const uint4*)(ySrc + kn + 12 * NN);
        }

        #pragma unroll
        for (int ks = 0; ks < 4; ++ks) {
            s16x8 af = *(const s16x8*)(aFragBase + ks * 32);
            s16x8 bf = *(const s16x8*)&Ys[yRow * 128 + ((ks * 32 + fg * 8) ^ ySwz)];
            acc = __builtin_amdgcn_mfma_f32_16x16x32_bf16(af, bf, acc, 0, 0, 0);
        }
    }

    // ---- epilogue: D map col = lane&15, row = (lane>>4)*4 + reg ----
    const int col = w * 16 + fr;
    const float bv = bias[col];
    #pragma unroll
    for (int r = 0; r < 4; ++r) {
        const int nrow = n0 + fg * 4 + r;
        const float di = dInv[(size_t)b * NN + nrow];
        float v = di * (acc[r] + Yf_b[(size_t)nrow * OO + col]) + bv;
        O_b[(size_t)nrow * OO + col] = (v >= 0.f) ? v : ALPHA * v;
    }
}

// ---------------------------------------------------------------------------
extern "C" void kernel_launch(void* const* d_in, const int* in_sizes, int n_in,
                              void* d_out, int out_size, void* d_ws, size_t ws_size,
                              hipStream_t stream) {
    const float* X    = (const float*)d_in[0];
    const float* A    = (const float*)d_in[1];
    const float* W    = (const float*)d_in[2];
    const float* bias = (const float*)d_in[3];

    float* out0 = (float*)d_out;                         // [B,N,O]
    float* outA = out0 + (size_t)BB * NN * OO;           // [B,N,N]  (= Ac)

    float*  dInv  = (float*)d_ws;                          // 16384 f32 (64 KB)
    float*  dsum4 = dInv + (size_t)BB * NN;                // 65536 f32 (256 KB)
    float*  Yf    = dsum4 + (size_t)BB * NN * 4;           // 4 MB
    ushort* Ytb   = (ushort*)(Yf + (size_t)BB * NN * OO);  // 2 MB

    k_copy4<<<BB * NN / 4, 256, 0, stream>>>(A, outA, dsum4);
    k_xw   <<<BB * NN / 16, 256, 0, stream>>>(X, W, dsum4, dInv, Yf, Ytb);
    k_main <<<BB * 128, 256, 0, stream>>>(outA, Ytb, Yf, dInv, bias, out0);
}

// Round 16
// 76.835 us; speedup vs baseline: 1.0725x; 1.0725x over previous
//
#include <hip/hip_runtime.h>
#include <math.h>

// Problem constants (B=8, N=2048, F=64, O=64), f32 in/out.
#define BB 8
#define NN 2048
#define FF 64
#define OO 64
#define KC 128                 // K-chunk per k_main phase
#define NITER (NN / KC)        // 16 (8 double-phases)
constexpr float ALPHA = 0.2f;

typedef float  f32x4  __attribute__((ext_vector_type(4)));
typedef short  s16x8  __attribute__((ext_vector_type(8)));

// round-to-nearest-even f32 -> bf16, two packed into a u32
static __device__ __forceinline__ unsigned int packbf2(float a, float b) {
    unsigned int ua = __builtin_bit_cast(unsigned int, a);
    unsigned int ub = __builtin_bit_cast(unsigned int, b);
    ua = (ua + 0x7FFFu + ((ua >> 16) & 1u)) >> 16;
    ub = (ub + 0x7FFFu + ((ub >> 16) & 1u)) & 0xFFFF0000u;
    return ua | ub;
}

// ---------------------------------------------------------------------------
// k_pre (R9 verbatim — measured best config, 77.06 us total):
// one block per row (16384 blocks).
//   - copy A -> outA with nt stores
//   - rowsum -> dInv[row]
//   - fused XW: y[o] = dInv * sum_f X[row,f] W[f,o] -> Yf (f32), Ytb (bf16 ^T)
// ---------------------------------------------------------------------------
__global__ __launch_bounds__(256) void k_pre(const float* __restrict__ A,
                                             const float* __restrict__ X,
                                             const float* __restrict__ W,
                                             float* __restrict__ Ac,
                                             float* __restrict__ dInvG,
                                             float* __restrict__ Yf,
                                             ushort* __restrict__ Ytb) {
    const int row = blockIdx.x;
    const float* a = A  + (size_t)row * NN;
    float*       c = Ac + (size_t)row * NN;
    const int t = threadIdx.x;

    __shared__ float partial[4];
    __shared__ float Xs[FF];
    __shared__ float dsh;

    f32x4 v0 = *(const f32x4*)(a + t * 4);
    f32x4 v1 = *(const f32x4*)(a + t * 4 + 1024);
    __builtin_nontemporal_store(v0, (f32x4*)(c + t * 4));
    __builtin_nontemporal_store(v1, (f32x4*)(c + t * 4 + 1024));

    // stage this row of X (64 f32 = 16 float4)
    if (t < 16) ((float4*)Xs)[t] = ((const float4*)(X + (size_t)row * FF))[t];

    float s = (v0.x + v0.y + v0.z + v0.w) + (v1.x + v1.y + v1.z + v1.w);
    #pragma unroll
    for (int off = 32; off > 0; off >>= 1) s += __shfl_down(s, off, 64);

    const int lane = t & 63, w = t >> 6;
    if (lane == 0) partial[w] = s;
    __syncthreads();
    if (t == 0) {
        float tot = partial[0] + partial[1] + partial[2] + partial[3] + 1.0f;
        float di = 1.0f / sqrtf(tot);
        dsh = di;
        dInvG[row] = di;
    }
    __syncthreads();

    // fused XW: wave 0, thread t = output column o
    if (t < OO) {
        float acc = 0.f;
        #pragma unroll 8
        for (int f = 0; f < FF; ++f) acc += Xs[f] * W[f * OO + t];
        float y = dsh * acc;
        Yf[(size_t)row * OO + t] = y;
        const int b = row >> 11;            // 2048 rows per batch
        const int n = row & (NN - 1);
        Ytb[((size_t)b * OO + t) * NN + n] = (ushort)packbf2(y, 0.f);
    }
}

// ---------------------------------------------------------------------------
// k_main (MFMA): out0[b,n,o] = leaky( dInv[n]*(sum_m A[n,m]*Y[m,o] + Y[n,o]) + bias[o] )
// Reads A (partially L3-resident under nt-store protection). No global
// stores in the K-loop. Depth-2 pipeline, R5-verified layout/swizzle.
// ---------------------------------------------------------------------------
__global__ __launch_bounds__(256, 4) void k_main(const float* __restrict__ A,
                                                 const ushort* __restrict__ Ytb,
                                                 const float* __restrict__ Yf,
                                                 const float* __restrict__ dInv,
                                                 const float* __restrict__ bias,
                                                 float* __restrict__ out0) {
    __shared__ ushort As[16][136];     // 4.25 KB
    __shared__ ushort Ys[64 * 128];    // 16 KB, [o][128], XOR-swizzled

    const int bx = blockIdx.x;          // 1024
    const int b  = bx >> 7;
    const int n0 = (bx & 127) * 16;

    const float*  Ab   = A    + ((size_t)b * NN + n0) * NN;
    const ushort* yb   = Ytb  + (size_t)b * OO * NN;
    const float*  Yf_b = Yf   + (size_t)b * NN * OO;
    float*        O_b  = out0 + (size_t)b * NN * OO;

    const int t = threadIdx.x;
    const int lane = t & 63, w = t >> 6;
    const int fr = lane & 15, fg = lane >> 4;

    // A staging coords (2 float4/thread)
    const int ar0 = t >> 5,         ac0 = (t & 31) * 4;
    const int ar1 = (t + 256) >> 5, ac1 = (t & 31) * 4;
    const float* aSrc0 = Ab + (size_t)ar0 * NN + ac0;
    const float* aSrc1 = Ab + (size_t)ar1 * NN + ac1;

    // Y staging coords (4 uint4/thread)
    const int yrBase = w * 16 + (lane >> 4);
    const int ycu    = (lane & 15) * 8;
    const ushort* ySrc = yb + (size_t)yrBase * NN + ycu;

    // fragment read bases
    const ushort* aFragBase = &As[fr][fg * 8];
    const int yRow = w * 16 + fr;
    const int ySwz = (fr & 7) << 3;

    f32x4 acc = {0.f, 0.f, 0.f, 0.f};

    // ---- two named prefetch sets (no runtime-indexed arrays) ----
    float4 paA0, paA1, paB0, paB1;
    uint4  pyA0, pyA1, pyA2, pyA3, pyB0, pyB1, pyB2, pyB3;

    // prologue: set A <- tile 0, set B <- tile 1
    paA0 = *(const float4*)(aSrc0);
    paA1 = *(const float4*)(aSrc1);
    pyA0 = *(const uint4*)(ySrc);
    pyA1 = *(const uint4*)(ySrc + 4 * NN);
    pyA2 = *(const uint4*)(ySrc + 8 * NN);
    pyA3 = *(const uint4*)(ySrc + 12 * NN);
    paB0 = *(const float4*)(aSrc0 + KC);
    paB1 = *(const float4*)(aSrc1 + KC);
    pyB0 = *(const uint4*)(ySrc + KC);
    pyB1 = *(const uint4*)(ySrc + KC + 4 * NN);
    pyB2 = *(const uint4*)(ySrc + KC + 8 * NN);
    pyB3 = *(const uint4*)(ySrc + KC + 12 * NN);

    for (int j = 0; j < NITER / 2; ++j) {
        const int k0 = 2 * j * KC;

        // ================= phase A: consume set A (tile 2j) =================
        __builtin_amdgcn_s_barrier();
        {
            uint2 qa;
            qa.x = packbf2(paA0.x, paA0.y);
            qa.y = packbf2(paA0.z, paA0.w);
            *(uint2*)&As[ar0][ac0] = qa;
            qa.x = packbf2(paA1.x, paA1.y);
            qa.y = packbf2(paA1.z, paA1.w);
            *(uint2*)&As[ar1][ac1] = qa;
        }
        {
            const int r0w = yrBase;
            *(uint4*)&Ys[(r0w + 0) * 128 + (ycu ^ (((r0w + 0) & 7) << 3))] = pyA0;
            *(uint4*)&Ys[(r0w + 4) * 128 + (ycu ^ (((r0w + 4) & 7) << 3))] = pyA1;
            *(uint4*)&Ys[(r0w + 8) * 128 + (ycu ^ (((r0w + 8) & 7) << 3))] = pyA2;
            *(uint4*)&Ys[(r0w + 12) * 128 + (ycu ^ (((r0w + 12) & 7) << 3))] = pyA3;
        }
        asm volatile("s_waitcnt lgkmcnt(0)" ::: "memory");
        __builtin_amdgcn_sched_barrier(0);
        __builtin_amdgcn_s_barrier();

        if (j < NITER / 2 - 1) {            // refill set A <- tile 2j+2
            const int kn = k0 + 2 * KC;
            paA0 = *(const float4*)(aSrc0 + kn);
            paA1 = *(const float4*)(aSrc1 + kn);
            pyA0 = *(const uint4*)(ySrc + kn);
            pyA1 = *(const uint4*)(ySrc + kn + 4 * NN);
            pyA2 = *(const uint4*)(ySrc + kn + 8 * NN);
            pyA3 = *(const uint4*)(ySrc + kn + 12 * NN);
        }

        #pragma unroll
        for (int ks = 0; ks < 4; ++ks) {
            s16x8 af = *(const s16x8*)(aFragBase + ks * 32);
            s16x8 bf = *(const s16x8*)&Ys[yRow * 128 + ((ks * 32 + fg * 8) ^ ySwz)];
            acc = __builtin_amdgcn_mfma_f32_16x16x32_bf16(af, bf, acc, 0, 0, 0);
        }

        // ================= phase B: consume set B (tile 2j+1) ===============
        __builtin_amdgcn_s_barrier();
        {
            uint2 qa;
            qa.x = packbf2(paB0.x, paB0.y);
            qa.y = packbf2(paB0.z, paB0.w);
            *(uint2*)&As[ar0][ac0] = qa;
            qa.x = packbf2(paB1.x, paB1.y);
            qa.y = packbf2(paB1.z, paB1.w);
            *(uint2*)&As[ar1][ac1] = qa;
        }
        {
            const int r0w = yrBase;
            *(uint4*)&Ys[(r0w + 0) * 128 + (ycu ^ (((r0w + 0) & 7) << 3))] = pyB0;
            *(uint4*)&Ys[(r0w + 4) * 128 + (ycu ^ (((r0w + 4) & 7) << 3))] = pyB1;
            *(uint4*)&Ys[(r0w + 8) * 128 + (ycu ^ (((r0w + 8) & 7) << 3))] = pyB2;
            *(uint4*)&Ys[(r0w + 12) * 128 + (ycu ^ (((r0w + 12) & 7) << 3))] = pyB3;
        }
        asm volatile("s_waitcnt lgkmcnt(0)" ::: "memory");
        __builtin_amdgcn_sched_barrier(0);
        __builtin_amdgcn_s_barrier();

        if (j < NITER / 2 - 1) {            // refill set B <- tile 2j+3
            const int kn = k0 + 3 * KC;
            paB0 = *(const float4*)(aSrc0 + kn);
            paB1 = *(const float4*)(aSrc1 + kn);
            pyB0 = *(const uint4*)(ySrc + kn);
            pyB1 = *(const uint4*)(ySrc + kn + 4 * NN);
            pyB2 = *(const uint4*)(ySrc + kn + 8 * NN);
            pyB3 = *(const uint4*)(ySrc + kn + 12 * NN);
        }

        #pragma unroll
        for (int ks = 0; ks < 4; ++ks) {
            s16x8 af = *(const s16x8*)(aFragBase + ks * 32);
            s16x8 bf = *(const s16x8*)&Ys[yRow * 128 + ((ks * 32 + fg * 8) ^ ySwz)];
            acc = __builtin_amdgcn_mfma_f32_16x16x32_bf16(af, bf, acc, 0, 0, 0);
        }
    }

    // ---- epilogue: D map col = lane&15, row = (lane>>4)*4 + reg ----
    const int col = w * 16 + fr;
    const float bv = bias[col];
    #pragma unroll
    for (int r = 0; r < 4; ++r) {
        const int nrow = n0 + fg * 4 + r;
        const float di = dInv[(size_t)b * NN + nrow];
        float v = di * (acc[r] + Yf_b[(size_t)nrow * OO + col]) + bv;
        O_b[(size_t)nrow * OO + col] = (v >= 0.f) ? v : ALPHA * v;
    }
}

// ---------------------------------------------------------------------------
extern "C" void kernel_launch(void* const* d_in, const int* in_sizes, int n_in,
                              void* d_out, int out_size, void* d_ws, size_t ws_size,
                              hipStream_t stream) {
    const float* X    = (const float*)d_in[0];
    const float* A    = (const float*)d_in[1];
    const float* W    = (const float*)d_in[2];
    const float* bias = (const float*)d_in[3];

    float* out0 = (float*)d_out;                         // [B,N,O]
    float* outA = out0 + (size_t)BB * NN * OO;           // [B,N,N]

    float*  dInv = (float*)d_ws;                         // 64 KB
    float*  Yf   = dInv + (size_t)BB * NN;               // 4 MB
    ushort* Ytb  = (ushort*)(Yf + (size_t)BB * NN * OO); // 2 MB

    k_pre <<<BB * NN, 256, 0, stream>>>(A, X, W, outA, dInv, Yf, Ytb);
    k_main<<<BB * 128, 256, 0, stream>>>(A, Ytb, Yf, dInv, bias, out0);
}